// Round 1
// baseline (2065.768 us; speedup 1.0000x reference)
//
#include <hip/hip_runtime.h>
#include <math.h>

#define B_    16
#define T_    4096
#define SEM   512
#define ACO   32
#define XROWS 544
#define CODES 2048
#define EPSC  1e-5f
#define HALFC 4.0f

// ---- workspace layout (floats) ----
// embT : [512][2048]  at ws + 0            (4 MiB)   embT[d][c] = esum[c][d]/clip(usage[c])
// bias : [2048]       at ws + 512*2048     (8 KiB)   bias[c] = 0.5*|e_c|^2
// codes: [16*4096] int after bias          (256 KiB)

// ============ kernel 1: per-code bias = 0.5*|e|^2 ============
__global__ void bias_kernel(const float* __restrict__ esum,
                            const float* __restrict__ usage,
                            float* __restrict__ bias) {
    int c = blockIdx.x;
    float u = fmaxf(usage[c], EPSC);
    float s = 0.f;
    for (int d = threadIdx.x; d < SEM; d += 64) {
        float v = esum[(size_t)c * SEM + d] / u;
        s += v * v;
    }
    for (int off = 32; off; off >>= 1) s += __shfl_down(s, off);
    if (threadIdx.x == 0) bias[c] = 0.5f * s;
}

// ============ kernel 2: embT[d][c] = esum[c][d] / clip(usage[c]) ============
__global__ void embT_kernel(const float* __restrict__ esum,
                            const float* __restrict__ usage,
                            float* __restrict__ embT) {
    __shared__ float tile[32][33];
    int c0 = blockIdx.x * 32;
    int d0 = blockIdx.y * 32;
    int col = threadIdx.x & 31, r = threadIdx.x >> 5;  // 256 threads: r=0..7
    for (int i = r; i < 32; i += 8) {
        float u = fmaxf(usage[c0 + i], EPSC);
        tile[col][i] = esum[(size_t)(c0 + i) * SEM + d0 + col] / u;
    }
    __syncthreads();
    for (int i = r; i < 32; i += 8)
        embT[(size_t)(d0 + i) * CODES + c0 + col] = tile[i][col];
}

// ============ kernel 3: fused GEMM + argmin ============
// score(m,c) = x_m . e_c - 0.5*|e_c|^2 ; argmax == argmin of d2.
// Block: 128 queries (consecutive t, one b) x all 2048 codes in chunks of 128.
#define MT 128
#define NT 128
#define KT 32
__global__ __launch_bounds__(256, 4) void argmin_kernel(
        const float* __restrict__ x, const float* __restrict__ embT,
        const float* __restrict__ bias, int* __restrict__ codes_ws,
        float* __restrict__ codes_out) {
    __shared__ float Xs[KT][MT];
    __shared__ float Es[KT][NT];
    int tid = threadIdx.x;
    int tx = tid & 15, ty = tid >> 4;
    int m0 = blockIdx.x * MT;
    int b  = m0 >> 12;        // /4096
    int t0 = m0 & 4095;
    const float* xbase = x + (size_t)b * XROWS * T_ + t0; // xbase[d*T_ + m]

    float best[8];
    int   bidx[8];
#pragma unroll
    for (int i = 0; i < 8; i++) { best[i] = -3.4e38f; bidx[i] = 0; }

    for (int n0 = 0; n0 < CODES; n0 += NT) {
        float acc[8][8];
#pragma unroll
        for (int i = 0; i < 8; i++)
#pragma unroll
            for (int j = 0; j < 8; j++) acc[i][j] = 0.f;

        for (int k0 = 0; k0 < SEM; k0 += KT) {
            __syncthreads();
#pragma unroll
            for (int p = 0; p < 4; p++) {
                int idx = p * 256 + tid;       // 0..1023
                int kk  = idx >> 5;            // row (0..31)
                int mq  = idx & 31;            // float4 within row
                float4 v = *(const float4*)(xbase + (size_t)(k0 + kk) * T_ + mq * 4);
                *(float4*)&Xs[kk][mq * 4] = v;
                float4 w = *(const float4*)(embT + (size_t)(k0 + kk) * CODES + n0 + mq * 4);
                *(float4*)&Es[kk][mq * 4] = w;
            }
            __syncthreads();
#pragma unroll
            for (int kk = 0; kk < KT; kk++) {
                float xa[8], ea[8];
                *(float4*)&xa[0] = *(const float4*)&Xs[kk][tx * 4];
                *(float4*)&xa[4] = *(const float4*)&Xs[kk][64 + tx * 4];
                *(float4*)&ea[0] = *(const float4*)&Es[kk][ty * 4];
                *(float4*)&ea[4] = *(const float4*)&Es[kk][64 + ty * 4];
#pragma unroll
                for (int i = 0; i < 8; i++)
#pragma unroll
                    for (int j = 0; j < 8; j++)
                        acc[i][j] = fmaf(xa[i], ea[j], acc[i][j]);
            }
        }
        // fold bias, update running argmax (per-thread n ascending -> '>' keeps smallest idx)
#pragma unroll
        for (int j = 0; j < 8; j++) {
            int n = n0 + ((j < 4) ? (ty * 4 + j) : (64 + ty * 4 + (j - 4)));
            float bsub = bias[n];
#pragma unroll
            for (int i = 0; i < 8; i++) {
                float s = acc[i][j] - bsub;
                if (s > best[i]) { best[i] = s; bidx[i] = n; }
            }
        }
    }

    // cross-thread (ty) reduction per query
    __syncthreads();
    float* sbest = &Xs[0][0];           // 16*128 floats fits (Xs = 32*128)
    int*   sidx  = (int*)&Es[0][0];
#pragma unroll
    for (int i = 0; i < 8; i++) {
        int m = (i < 4) ? (tx * 4 + i) : (64 + tx * 4 + (i - 4));
        sbest[ty * MT + m] = best[i];
        sidx [ty * MT + m] = bidx[i];
    }
    __syncthreads();
    if (tid < MT) {
        int m = tid;
        float bb = sbest[m]; int bi = sidx[m];
        for (int r = 1; r < 16; r++) {
            float v = sbest[r * MT + m]; int vi = sidx[r * MT + m];
            if (v > bb || (v == bb && vi < bi)) { bb = v; bi = vi; }
        }
        codes_ws[m0 + m] = bi;
        // codes output row 0 of [b][33][t]
        codes_out[(size_t)b * 33 * T_ + (t0 + m)] = (float)bi;
    }
}

// ============ kernel 4: finalize (sem select/gather + aco path) ============
__global__ void finalize_kernel(const float* __restrict__ x,
                                const float* __restrict__ embT,
                                const int* __restrict__ codes_ws,
                                const float* __restrict__ noise,
                                const float* __restrict__ probs_sem,
                                const float* __restrict__ probs_aco,
                                float* __restrict__ out,
                                float* __restrict__ codes_out) {
    const size_t N0 = (size_t)B_ * SEM * T_;   // 33,554,432
    const size_t N1 = (size_t)B_ * ACO * T_;   // 2,097,152
    size_t idx = (size_t)blockIdx.x * 256 + threadIdx.x;
    if (idx < N0) {
        int t = (int)(idx & 4095);
        int d = (int)((idx >> 12) & 511);
        int b = (int)(idx >> 21);
        float v;
        if (probs_sem[b] < 0.5f) {
            int c = codes_ws[(b << 12) + t];
            v = embT[(size_t)d * CODES + c];
        } else {
            v = x[((size_t)(b * XROWS + d)) * T_ + t];
        }
        out[((size_t)(b * XROWS + d)) * T_ + t] = v;
    } else if (idx < N0 + N1) {
        size_t i2 = idx - N0;
        int t = (int)(i2 & 4095);
        int j = (int)((i2 >> 12) & 31);
        int b = (int)(i2 >> 17);
        float a  = x[((size_t)(b * XROWS + SEM + j)) * T_ + t];
        float zb = tanhf(a) * HALFC;
        float p  = probs_aco[b];
        float zo;
        if (p < 0.5f) {
            zo = rintf(zb);                         // round-half-even, matches jnp.round
        } else if (p < 0.75f) {
            float nz = noise[((size_t)(b * ACO + j)) * T_ + t];
            float ns = ((nz * 2.0f - 1.0f) * (float)(1.0 / 9.0)) * HALFC;
            zo = fminf(fmaxf(zb + ns, -HALFC), HALFC);
        } else {
            zo = zb;
        }
        float code = fminf(fmaxf(rintf(zo + HALFC), 0.f), 8.f);
        out[((size_t)(b * XROWS + SEM + j)) * T_ + t] = zo * 0.25f;
        codes_out[((size_t)(b * 33 + 1 + j)) * T_ + t] = code;
    }
}

extern "C" void kernel_launch(void* const* d_in, const int* in_sizes, int n_in,
                              void* d_out, int out_size, void* d_ws, size_t ws_size,
                              hipStream_t stream) {
    const float* x      = (const float*)d_in[0];
    const float* esum   = (const float*)d_in[1];
    const float* usage  = (const float*)d_in[2];
    const float* noise  = (const float*)d_in[3];
    const float* psem   = (const float*)d_in[4];
    const float* paco   = (const float*)d_in[5];
    float* out = (float*)d_out;

    float* embT   = (float*)d_ws;
    float* bias   = embT + (size_t)SEM * CODES;
    int*   codesW = (int*)(bias + CODES);

    const size_t QOFF = (size_t)B_ * XROWS * T_;   // 35,651,584
    float* codes_out = out + QOFF;

    bias_kernel<<<CODES, 64, 0, stream>>>(esum, usage, bias);
    embT_kernel<<<dim3(CODES / 32, SEM / 32), 256, 0, stream>>>(esum, usage, embT);
    argmin_kernel<<<(B_ * T_) / MT, 256, 0, stream>>>(x, embT, bias, codesW, codes_out);
    const size_t NTOT = (size_t)B_ * SEM * T_ + (size_t)B_ * ACO * T_;
    finalize_kernel<<<(int)(NTOT / 256), 256, 0, stream>>>(x, embT, codesW, noise,
                                                           psem, paco, out, codes_out);
}